// Round 3
// baseline (8855.564 us; speedup 1.0000x reference)
//
#include <hip/hip_runtime.h>

// Problem constants (fixed by the reference).
constexpr int Bn = 8192;   // batch
constexpr int Dd = 2048;   // activation dim
constexpr int Ff = 16384;  // dict size
constexpr int Kk = 64;     // top-k
constexpr int NC = 128;    // screening candidates per row (superset of true top-K)
constexpr int KC = 384;    // OpenBLAS SGEMM_DEFAULT_Q (k-panel size) being emulated

// ---------------------------------------------------------------------------
// Transpose W_dec [D,F] -> Wt [F,D] so decode reads rows contiguously.
// ---------------------------------------------------------------------------
__global__ __launch_bounds__(256) void transpose_kernel(const float* __restrict__ Wdec,
                                                        float* __restrict__ Wt) {
  __shared__ float t[32][33];
  const int x = threadIdx.x, y = threadIdx.y;
  const int f0 = blockIdx.x * 32, d0 = blockIdx.y * 32;
#pragma unroll
  for (int i = 0; i < 4; ++i)
    t[y + i * 8][x] = Wdec[(size_t)(d0 + y + i * 8) * Ff + f0 + x];
  __syncthreads();
#pragma unroll
  for (int i = 0; i < 4; ++i)
    Wt[(size_t)(f0 + y + i * 8) * Dd + d0 + x] = t[x][y + i * 8];
}

// ---------------------------------------------------------------------------
// Encode GEMM (fp32 screen only — its values never reach the output):
// pre[b,f] = sum_d (x[b,d]-b_dec[d])*W_enc[f,d] + b_enc[f]
// 128x128 tile, BK=16, 256 threads, 8x8 micro-tile. pre is chunk-local.
// ---------------------------------------------------------------------------
__global__ __launch_bounds__(256) void encode_gemm(const float* __restrict__ x,
                                                   const float* __restrict__ W,
                                                   const float* __restrict__ bdec,
                                                   const float* __restrict__ benc,
                                                   float* __restrict__ pre, int row0) {
  __shared__ float As[16][132];
  __shared__ float Bs[16][132];
  const int tid = threadIdx.x;
  const int ty = tid >> 4, tx = tid & 15;
  const int m0 = row0 + blockIdx.y * 128;
  const int n0 = blockIdx.x * 128;
  float acc[8][8] = {};

  for (int k0 = 0; k0 < Dd; k0 += 16) {
#pragma unroll
    for (int i = 0; i < 2; ++i) {
      const int f4 = tid + i * 256;
      const int r = f4 >> 2;
      const int c = (f4 & 3) << 2;
      const float4 xv = *(const float4*)(x + (size_t)(m0 + r) * Dd + k0 + c);
      const float4 bd = *(const float4*)(bdec + k0 + c);
      As[c + 0][r] = xv.x - bd.x;
      As[c + 1][r] = xv.y - bd.y;
      As[c + 2][r] = xv.z - bd.z;
      As[c + 3][r] = xv.w - bd.w;
      const float4 wv = *(const float4*)(W + (size_t)(n0 + r) * Dd + k0 + c);
      Bs[c + 0][r] = wv.x;
      Bs[c + 1][r] = wv.y;
      Bs[c + 2][r] = wv.z;
      Bs[c + 3][r] = wv.w;
    }
    __syncthreads();
#pragma unroll
    for (int k = 0; k < 16; ++k) {
      float a[8], b[8];
      *(float4*)&a[0] = *(const float4*)&As[k][ty * 8];
      *(float4*)&a[4] = *(const float4*)&As[k][ty * 8 + 4];
      *(float4*)&b[0] = *(const float4*)&Bs[k][tx * 8];
      *(float4*)&b[4] = *(const float4*)&Bs[k][tx * 8 + 4];
#pragma unroll
      for (int i = 0; i < 8; ++i)
#pragma unroll
        for (int j = 0; j < 8; ++j) acc[i][j] += a[i] * b[j];
    }
    __syncthreads();
  }

  const int lr0 = blockIdx.y * 128 + ty * 8;
#pragma unroll
  for (int i = 0; i < 8; ++i) {
#pragma unroll
    for (int jj = 0; jj < 2; ++jj) {
      const float4 be = *(const float4*)(benc + n0 + tx * 8 + jj * 4);
      float4 o;
      o.x = acc[i][jj * 4 + 0] + be.x;
      o.y = acc[i][jj * 4 + 1] + be.y;
      o.z = acc[i][jj * 4 + 2] + be.z;
      o.w = acc[i][jj * 4 + 3] + be.w;
      *(float4*)(pre + (size_t)(lr0 + i) * Ff + n0 + tx * 8 + jj * 4) = o;
    }
  }
}

// ---------------------------------------------------------------------------
// Screen: per-row top-NC candidate set via 4-pass radix select on
// order-preserving uint32 keys. One block (256 threads) per row.
// Only the candidate INDEX SET matters (np-emulating rescore follows).
// ---------------------------------------------------------------------------
__device__ __forceinline__ unsigned f2u(float f) {
  unsigned b = __float_as_uint(f);
  return (b & 0x80000000u) ? ~b : (b | 0x80000000u);
}

__global__ __launch_bounds__(256) void screen_kernel(const float* __restrict__ pre,
                                                     int* __restrict__ cand, int row0) {
  const int tid = threadIdx.x;
  const int lrow = blockIdx.x;
  const int grow = row0 + lrow;
  const float* rowp = pre + (size_t)lrow * Ff;

  unsigned u[64];
#pragma unroll
  for (int j = 0; j < 64; ++j) u[j] = f2u(rowp[tid + j * 256]);

  __shared__ unsigned hist[256];
  __shared__ unsigned scan[256];
  __shared__ int sh_sel, sh_above;

  unsigned prefix = 0;
  int need = NC;
#pragma unroll
  for (int pass = 0; pass < 4; ++pass) {
    const int shift = 24 - 8 * pass;
    hist[tid] = 0;
    __syncthreads();
#pragma unroll
    for (int j = 0; j < 64; ++j) {
      const bool match = (pass == 0) || ((u[j] >> (shift + 8)) == (prefix >> (shift + 8)));
      if (match) atomicAdd(&hist[(u[j] >> shift) & 255u], 1u);
    }
    __syncthreads();
    scan[tid] = hist[tid];
    __syncthreads();
    for (int off = 1; off < 256; off <<= 1) {
      const unsigned v = (tid + off < 256) ? scan[tid + off] : 0u;
      __syncthreads();
      scan[tid] += v;
      __syncthreads();
    }
    const unsigned above = (tid == 255) ? 0u : scan[tid + 1];
    if (scan[tid] >= (unsigned)need && above < (unsigned)need) {
      sh_sel = tid;
      sh_above = (int)above;
    }
    __syncthreads();
    prefix |= ((unsigned)sh_sel) << shift;
    need -= sh_above;
    __syncthreads();
  }

  const unsigned T = prefix;       // key of the NC-th largest element
  __shared__ int cnt_gt, cnt_eq;
  if (tid == 0) { cnt_gt = 0; cnt_eq = 0; }
  __syncthreads();
  const int base_eq = NC - need;   // count strictly greater than T
#pragma unroll
  for (int j = 0; j < 64; ++j) {
    if (u[j] > T) {
      const int p = atomicAdd(&cnt_gt, 1);
      if (p < NC) cand[(size_t)grow * NC + p] = tid + j * 256;
    }
  }
  __syncthreads();
#pragma unroll
  for (int j = 0; j < 64; ++j) {
    if (u[j] == T) {
      const int p = atomicAdd(&cnt_eq, 1);
      if (p < need) cand[(size_t)grow * NC + base_eq + p] = tid + j * 256;
    }
  }
}

// ---------------------------------------------------------------------------
// Rescore NC candidates per row, bit-emulating numpy/OpenBLAS fp32 sgemm:
// per element, K is processed in panels of KC=384; within a panel a single
// sequential fused-FMA chain in ascending k; panel sums added with plain
// fp32 adds. Then exact top-K of the candidate scores (desc, idx asc).
// One block of 128 threads per row; thread t owns candidate t (its chain
// must stay strictly sequential in one accumulator).
// ---------------------------------------------------------------------------
__global__ __launch_bounds__(128) void rescore_np(const float* __restrict__ x,
                                                  const float* __restrict__ Wenc,
                                                  const float* __restrict__ bdec,
                                                  const float* __restrict__ benc,
                                                  const int* __restrict__ cand,
                                                  float* __restrict__ vals,
                                                  int* __restrict__ idxs) {
  const int row = blockIdx.x;
  const int t = threadIdx.x;
  __shared__ float xs[Dd];
  __shared__ float sc[NC];
  __shared__ int ci[NC];

#pragma unroll
  for (int i = 0; i < 4; ++i) {
    const int d = t * 4 + i * 512;
    const float4 v = *(const float4*)(x + (size_t)row * Dd + d);
    const float4 b = *(const float4*)(bdec + d);
    xs[d + 0] = v.x - b.x;
    xs[d + 1] = v.y - b.y;
    xs[d + 2] = v.z - b.z;
    xs[d + 3] = v.w - b.w;
  }
  ci[t] = cand[(size_t)row * NC + t];
  __syncthreads();

  const int f = ci[t];
  const float* w = Wenc + (size_t)f * Dd;
  float accT = 0.0f;   // C accumulator across k-panels (plain adds)
  float accB = 0.0f;   // within-panel sequential FMA chain

  for (int k0 = 0; k0 < Dd; k0 += 16) {
    const float4 w0 = *(const float4*)(w + k0);
    const float4 w1 = *(const float4*)(w + k0 + 4);
    const float4 w2 = *(const float4*)(w + k0 + 8);
    const float4 w3 = *(const float4*)(w + k0 + 12);
    accB = fmaf(xs[k0 + 0],  w0.x, accB);
    accB = fmaf(xs[k0 + 1],  w0.y, accB);
    accB = fmaf(xs[k0 + 2],  w0.z, accB);
    accB = fmaf(xs[k0 + 3],  w0.w, accB);
    accB = fmaf(xs[k0 + 4],  w1.x, accB);
    accB = fmaf(xs[k0 + 5],  w1.y, accB);
    accB = fmaf(xs[k0 + 6],  w1.z, accB);
    accB = fmaf(xs[k0 + 7],  w1.w, accB);
    accB = fmaf(xs[k0 + 8],  w2.x, accB);
    accB = fmaf(xs[k0 + 9],  w2.y, accB);
    accB = fmaf(xs[k0 + 10], w2.z, accB);
    accB = fmaf(xs[k0 + 11], w2.w, accB);
    accB = fmaf(xs[k0 + 12], w3.x, accB);
    accB = fmaf(xs[k0 + 13], w3.y, accB);
    accB = fmaf(xs[k0 + 14], w3.z, accB);
    accB = fmaf(xs[k0 + 15], w3.w, accB);
    const int ke = k0 + 16;
    if (ke % KC == 0 || ke == Dd) {   // close the k-panel (KC grid + tail)
      accT = accT + accB;
      accB = 0.0f;
    }
  }
  sc[t] = accT + benc[f];
  __syncthreads();

  // exact top-K of NC by (score desc, index asc); rank = collision-free slot
  const float s = sc[t];
  int cnt = 0;
  for (int j = 0; j < NC; ++j) {
    const float sj = sc[j];
    if (sj > s || (sj == s && ci[j] < f)) ++cnt;
  }
  if (cnt < Kk) {
    vals[(size_t)row * Kk + cnt] = s;
    idxs[(size_t)row * Kk + cnt] = f;
  }
}

// ---------------------------------------------------------------------------
// Decode: out[b,:] = b_dec + sum_k vals[b,k] * Wt[idx[b,k], :]
// ---------------------------------------------------------------------------
__global__ __launch_bounds__(256) void decode_kernel(const float* __restrict__ vals,
                                                     const int* __restrict__ idxs,
                                                     const float* __restrict__ Wt,
                                                     const float* __restrict__ bdec,
                                                     float* __restrict__ out) {
  const int row = blockIdx.x;
  const int tid = threadIdx.x;
  __shared__ float sv[Kk];
  __shared__ int si[Kk];
  if (tid < Kk) {
    sv[tid] = vals[(size_t)row * Kk + tid];
    si[tid] = idxs[(size_t)row * Kk + tid];
  }
  __syncthreads();
  const int d0 = tid * 4;
  float4 acc0 = *(const float4*)(bdec + d0);
  float4 acc1 = *(const float4*)(bdec + d0 + 1024);
#pragma unroll 4
  for (int k = 0; k < Kk; ++k) {
    const float v = sv[k];
    const float* w = Wt + (size_t)si[k] * Dd;
    const float4 w0 = *(const float4*)(w + d0);
    const float4 w1 = *(const float4*)(w + d0 + 1024);
    acc0.x += v * w0.x; acc0.y += v * w0.y; acc0.z += v * w0.z; acc0.w += v * w0.w;
    acc1.x += v * w1.x; acc1.y += v * w1.y; acc1.z += v * w1.z; acc1.w += v * w1.w;
  }
  *(float4*)(out + (size_t)row * Dd + d0) = acc0;
  *(float4*)(out + (size_t)row * Dd + d0 + 1024) = acc1;
}

// ---------------------------------------------------------------------------
// Workspace layout:
//   Wt (F*D fp32, 128 MiB) | cand (B*NC int) | vals (B*K) | idxs (B*K)
//   | pre chunk (rows_per_chunk * F fp32)
// ---------------------------------------------------------------------------
extern "C" void kernel_launch(void* const* d_in, const int* in_sizes, int n_in,
                              void* d_out, int out_size, void* d_ws, size_t ws_size,
                              hipStream_t stream) {
  (void)in_sizes; (void)n_in; (void)out_size;
  const float* x    = (const float*)d_in[0];
  const float* Wenc = (const float*)d_in[1];
  const float* benc = (const float*)d_in[2];
  const float* Wdec = (const float*)d_in[3];
  const float* bdec = (const float*)d_in[4];
  float* out = (float*)d_out;

  char* ws = (char*)d_ws;
  size_t off = 0;
  float* Wt   = (float*)(ws + off); off += (size_t)Ff * Dd * 4;
  int*   cand = (int*)(ws + off);   off += (size_t)Bn * NC * 4;
  float* vals = (float*)(ws + off); off += (size_t)Bn * Kk * 4;
  int*   idxs = (int*)(ws + off);   off += (size_t)Bn * Kk * 4;
  float* pre  = (float*)(ws + off);
  const size_t avail = ws_size > off ? ws_size - off : 0;
  int rpc = (int)(avail / ((size_t)Ff * 4));
  rpc = (rpc / 128) * 128;
  if (rpc < 128) rpc = 128;
  if (rpc > Bn) rpc = Bn;

  transpose_kernel<<<dim3(Ff / 32, Dd / 32), dim3(32, 8), 0, stream>>>(Wdec, Wt);

  for (int r0 = 0; r0 < Bn; r0 += rpc) {
    const int rows = (Bn - r0 < rpc) ? (Bn - r0) : rpc;
    encode_gemm<<<dim3(Ff / 128, rows / 128), 256, 0, stream>>>(x, Wenc, bdec, benc, pre, r0);
    screen_kernel<<<rows, 256, 0, stream>>>(pre, cand, r0);
  }

  rescore_np<<<Bn, 128, 0, stream>>>(x, Wenc, bdec, benc, cand, vals, idxs);
  decode_kernel<<<Bn, 256, 0, stream>>>(vals, idxs, Wt, bdec, out);
}

// Round 4
// 3149.196 us; speedup vs baseline: 2.8120x; 2.8120x over previous
//
#include <hip/hip_runtime.h>

// Problem constants (fixed by the reference).
constexpr int Bn = 8192;   // batch
constexpr int Dd = 2048;   // activation dim
constexpr int Ff = 16384;  // dict size
constexpr int Kk = 64;     // top-k
constexpr int NC = 128;    // screening candidates per row (superset of true top-K)
constexpr int KC = 384;    // OpenBLAS SGEMM_DEFAULT_Q (k-panel size) being emulated

typedef short bf16x8 __attribute__((ext_vector_type(8)));
typedef float f32x4 __attribute__((ext_vector_type(4)));

__device__ __forceinline__ short f2bf(float f) {   // fp32 -> bf16 RNE
  unsigned u = __float_as_uint(f);
  u += 0x7fffu + ((u >> 16) & 1u);
  return (short)(u >> 16);
}

// ---------------------------------------------------------------------------
// fp32 -> bf16 conversions for the MFMA screen. x also subtracts b_dec.
// ---------------------------------------------------------------------------
__global__ __launch_bounds__(256) void cvt_x_kernel(const float* __restrict__ x,
                                                    const float* __restrict__ bdec,
                                                    short* __restrict__ xb) {
  const long i = ((long)blockIdx.x * 256 + threadIdx.x) * 4;
  const float4 v = *(const float4*)(x + i);
  const float4 b = *(const float4*)(bdec + (int)(i & (Dd - 1)));
  short4 o;
  o.x = f2bf(v.x - b.x);
  o.y = f2bf(v.y - b.y);
  o.z = f2bf(v.z - b.z);
  o.w = f2bf(v.w - b.w);
  *(short4*)(xb + i) = o;
}

__global__ __launch_bounds__(256) void cvt_w_kernel(const float* __restrict__ w,
                                                    short* __restrict__ wb) {
  const long i = ((long)blockIdx.x * 256 + threadIdx.x) * 4;
  const float4 v = *(const float4*)(w + i);
  short4 o;
  o.x = f2bf(v.x);
  o.y = f2bf(v.y);
  o.z = f2bf(v.z);
  o.w = f2bf(v.w);
  *(short4*)(wb + i) = o;
}

// ---------------------------------------------------------------------------
// Transpose W_dec [D,F] -> Wt [F,D] so decode reads rows contiguously.
// ---------------------------------------------------------------------------
__global__ __launch_bounds__(256) void transpose_kernel(const float* __restrict__ Wdec,
                                                        float* __restrict__ Wt) {
  __shared__ float t[32][33];
  const int x = threadIdx.x, y = threadIdx.y;
  const int f0 = blockIdx.x * 32, d0 = blockIdx.y * 32;
#pragma unroll
  for (int i = 0; i < 4; ++i)
    t[y + i * 8][x] = Wdec[(size_t)(d0 + y + i * 8) * Ff + f0 + x];
  __syncthreads();
#pragma unroll
  for (int i = 0; i < 4; ++i)
    Wt[(size_t)(f0 + y + i * 8) * Dd + d0 + x] = t[x][y + i * 8];
}

// ---------------------------------------------------------------------------
// Encode screen GEMM in bf16 MFMA (values are screen-only; exact values come
// from rescore_np). pre[b,f] ~= sum_d xb[b,d]*wb[f,d] + benc[f].
// 128x128 tile, BK=32, 256 threads = 4 waves (2x2), each wave 64x64 via
// 4x4 grid of mfma_f32_16x16x32_bf16. global_load_lds width-16 staging.
// ---------------------------------------------------------------------------
__global__ __launch_bounds__(256) void encode_mfma(const short* __restrict__ A,
                                                   const short* __restrict__ Bw,
                                                   const float* __restrict__ benc,
                                                   float* __restrict__ pre) {
  __shared__ __align__(16) short As[128 * 32];
  __shared__ __align__(16) short Bs[128 * 32];
  const int tid = threadIdx.x;
  const int wave = tid >> 6, lane = tid & 63;
  const int quad = lane >> 4, l16 = lane & 15;
  const int m0 = blockIdx.y * 128;   // chunk-local batch-row base
  const int n0 = blockIdx.x * 128;   // feature base
  const int wm = (wave & 1) * 64, wn = (wave >> 1) * 64;

  const int lr = lane >> 2;          // staging: row within 16-row group
  const int lk = (lane & 3) * 8;     // staging: k-offset (elements)

  f32x4 acc[4][4] = {};

  for (int k0 = 0; k0 < Dd; k0 += 32) {
#pragma unroll
    for (int c = 0; c < 2; ++c) {
      const int rb = (wave * 2 + c) * 16;   // wave-uniform 16-row group
      __builtin_amdgcn_global_load_lds(
          (const __attribute__((address_space(1))) unsigned*)(A + (size_t)(m0 + rb + lr) * Dd + k0 + lk),
          (__attribute__((address_space(3))) unsigned*)(As + rb * 32),
          16, 0, 0);
      __builtin_amdgcn_global_load_lds(
          (const __attribute__((address_space(1))) unsigned*)(Bw + (size_t)(n0 + rb + lr) * Dd + k0 + lk),
          (__attribute__((address_space(3))) unsigned*)(Bs + rb * 32),
          16, 0, 0);
    }
    __syncthreads();
    bf16x8 af[4], bfr[4];
#pragma unroll
    for (int i = 0; i < 4; ++i) {
      af[i]  = *(const bf16x8*)(As + (wm + i * 16 + l16) * 32 + quad * 8);
      bfr[i] = *(const bf16x8*)(Bs + (wn + i * 16 + l16) * 32 + quad * 8);
    }
#pragma unroll
    for (int i = 0; i < 4; ++i)
#pragma unroll
      for (int j = 0; j < 4; ++j)
        acc[i][j] = __builtin_amdgcn_mfma_f32_16x16x32_bf16(af[i], bfr[j], acc[i][j], 0, 0, 0);
    __syncthreads();
  }

  // C/D layout: col = lane&15, row = quad*4 + reg  [learn_hip m89/m91]
#pragma unroll
  for (int j = 0; j < 4; ++j) {
    const int col = n0 + wn + j * 16 + l16;
    const float bj = benc[col];
#pragma unroll
    for (int i = 0; i < 4; ++i) {
      const int r0 = m0 + wm + i * 16 + quad * 4;
#pragma unroll
      for (int r = 0; r < 4; ++r)
        pre[(size_t)(r0 + r) * Ff + col] = acc[i][j][r] + bj;
    }
  }
}

// ---------------------------------------------------------------------------
// Screen: per-row top-NC candidate set via 4-pass radix select on
// order-preserving uint32 keys. One block (256 threads) per row.
// Only the candidate INDEX SET matters (np-emulating rescore follows).
// ---------------------------------------------------------------------------
__device__ __forceinline__ unsigned f2u(float f) {
  unsigned b = __float_as_uint(f);
  return (b & 0x80000000u) ? ~b : (b | 0x80000000u);
}

__global__ __launch_bounds__(256) void screen_kernel(const float* __restrict__ pre,
                                                     int* __restrict__ cand, int row0) {
  const int tid = threadIdx.x;
  const int lrow = blockIdx.x;
  const int grow = row0 + lrow;
  const float* rowp = pre + (size_t)lrow * Ff;

  unsigned u[64];
#pragma unroll
  for (int j = 0; j < 64; ++j) u[j] = f2u(rowp[tid + j * 256]);

  __shared__ unsigned hist[256];
  __shared__ unsigned scan[256];
  __shared__ int sh_sel, sh_above;

  unsigned prefix = 0;
  int need = NC;
#pragma unroll
  for (int pass = 0; pass < 4; ++pass) {
    const int shift = 24 - 8 * pass;
    hist[tid] = 0;
    __syncthreads();
#pragma unroll
    for (int j = 0; j < 64; ++j) {
      const bool match = (pass == 0) || ((u[j] >> (shift + 8)) == (prefix >> (shift + 8)));
      if (match) atomicAdd(&hist[(u[j] >> shift) & 255u], 1u);
    }
    __syncthreads();
    scan[tid] = hist[tid];
    __syncthreads();
    for (int off = 1; off < 256; off <<= 1) {
      const unsigned v = (tid + off < 256) ? scan[tid + off] : 0u;
      __syncthreads();
      scan[tid] += v;
      __syncthreads();
    }
    const unsigned above = (tid == 255) ? 0u : scan[tid + 1];
    if (scan[tid] >= (unsigned)need && above < (unsigned)need) {
      sh_sel = tid;
      sh_above = (int)above;
    }
    __syncthreads();
    prefix |= ((unsigned)sh_sel) << shift;
    need -= sh_above;
    __syncthreads();
  }

  const unsigned T = prefix;       // key of the NC-th largest element
  __shared__ int cnt_gt, cnt_eq;
  if (tid == 0) { cnt_gt = 0; cnt_eq = 0; }
  __syncthreads();
  const int base_eq = NC - need;   // count strictly greater than T
#pragma unroll
  for (int j = 0; j < 64; ++j) {
    if (u[j] > T) {
      const int p = atomicAdd(&cnt_gt, 1);
      if (p < NC) cand[(size_t)grow * NC + p] = tid + j * 256;
    }
  }
  __syncthreads();
#pragma unroll
  for (int j = 0; j < 64; ++j) {
    if (u[j] == T) {
      const int p = atomicAdd(&cnt_eq, 1);
      if (p < need) cand[(size_t)grow * NC + base_eq + p] = tid + j * 256;
    }
  }
}

// ---------------------------------------------------------------------------
// Rescore NC candidates per row, bit-emulating numpy/OpenBLAS fp32 sgemm:
// KC=384 k-panels, sequential FMA chain within a panel, plain adds across.
// Then exact top-K of candidate scores (desc, idx asc).
// ---------------------------------------------------------------------------
__global__ __launch_bounds__(128) void rescore_np(const float* __restrict__ x,
                                                  const float* __restrict__ Wenc,
                                                  const float* __restrict__ bdec,
                                                  const float* __restrict__ benc,
                                                  const int* __restrict__ cand,
                                                  float* __restrict__ vals,
                                                  int* __restrict__ idxs) {
  const int row = blockIdx.x;
  const int t = threadIdx.x;
  __shared__ float xs[Dd];
  __shared__ float sc[NC];
  __shared__ int ci[NC];

#pragma unroll
  for (int i = 0; i < 4; ++i) {
    const int d = t * 4 + i * 512;
    const float4 v = *(const float4*)(x + (size_t)row * Dd + d);
    const float4 b = *(const float4*)(bdec + d);
    xs[d + 0] = v.x - b.x;
    xs[d + 1] = v.y - b.y;
    xs[d + 2] = v.z - b.z;
    xs[d + 3] = v.w - b.w;
  }
  ci[t] = cand[(size_t)row * NC + t];
  __syncthreads();

  const int f = ci[t];
  const float* w = Wenc + (size_t)f * Dd;
  float accT = 0.0f;   // across-panel accumulator (plain adds)
  float accB = 0.0f;   // within-panel sequential FMA chain

  for (int k0 = 0; k0 < Dd; k0 += 16) {
    const float4 w0 = *(const float4*)(w + k0);
    const float4 w1 = *(const float4*)(w + k0 + 4);
    const float4 w2 = *(const float4*)(w + k0 + 8);
    const float4 w3 = *(const float4*)(w + k0 + 12);
    accB = fmaf(xs[k0 + 0],  w0.x, accB);
    accB = fmaf(xs[k0 + 1],  w0.y, accB);
    accB = fmaf(xs[k0 + 2],  w0.z, accB);
    accB = fmaf(xs[k0 + 3],  w0.w, accB);
    accB = fmaf(xs[k0 + 4],  w1.x, accB);
    accB = fmaf(xs[k0 + 5],  w1.y, accB);
    accB = fmaf(xs[k0 + 6],  w1.z, accB);
    accB = fmaf(xs[k0 + 7],  w1.w, accB);
    accB = fmaf(xs[k0 + 8],  w2.x, accB);
    accB = fmaf(xs[k0 + 9],  w2.y, accB);
    accB = fmaf(xs[k0 + 10], w2.z, accB);
    accB = fmaf(xs[k0 + 11], w2.w, accB);
    accB = fmaf(xs[k0 + 12], w3.x, accB);
    accB = fmaf(xs[k0 + 13], w3.y, accB);
    accB = fmaf(xs[k0 + 14], w3.z, accB);
    accB = fmaf(xs[k0 + 15], w3.w, accB);
    const int ke = k0 + 16;
    if (ke % KC == 0 || ke == Dd) {   // close the k-panel (KC grid + tail)
      accT = accT + accB;
      accB = 0.0f;
    }
  }
  sc[t] = accT + benc[f];
  __syncthreads();

  const float s = sc[t];
  int cnt = 0;
  for (int j = 0; j < NC; ++j) {
    const float sj = sc[j];
    if (sj > s || (sj == s && ci[j] < f)) ++cnt;
  }
  if (cnt < Kk) {
    vals[(size_t)row * Kk + cnt] = s;
    idxs[(size_t)row * Kk + cnt] = f;
  }
}

// ---------------------------------------------------------------------------
// Decode: out[b,:] = b_dec + sum_k vals[b,k] * Wt[idx[b,k], :]
// ---------------------------------------------------------------------------
__global__ __launch_bounds__(256) void decode_kernel(const float* __restrict__ vals,
                                                     const int* __restrict__ idxs,
                                                     const float* __restrict__ Wt,
                                                     const float* __restrict__ bdec,
                                                     float* __restrict__ out) {
  const int row = blockIdx.x;
  const int tid = threadIdx.x;
  __shared__ float sv[Kk];
  __shared__ int si[Kk];
  if (tid < Kk) {
    sv[tid] = vals[(size_t)row * Kk + tid];
    si[tid] = idxs[(size_t)row * Kk + tid];
  }
  __syncthreads();
  const int d0 = tid * 4;
  float4 acc0 = *(const float4*)(bdec + d0);
  float4 acc1 = *(const float4*)(bdec + d0 + 1024);
#pragma unroll 4
  for (int k = 0; k < Kk; ++k) {
    const float v = sv[k];
    const float* w = Wt + (size_t)si[k] * Dd;
    const float4 w0 = *(const float4*)(w + d0);
    const float4 w1 = *(const float4*)(w + d0 + 1024);
    acc0.x += v * w0.x; acc0.y += v * w0.y; acc0.z += v * w0.z; acc0.w += v * w0.w;
    acc1.x += v * w1.x; acc1.y += v * w1.y; acc1.z += v * w1.z; acc1.w += v * w1.w;
  }
  *(float4*)(out + (size_t)row * Dd + d0) = acc0;
  *(float4*)(out + (size_t)row * Dd + d0 + 1024) = acc1;
}

// ---------------------------------------------------------------------------
// Workspace layout:
//   xb (B*D bf16, 32 MiB) | wb (F*D bf16, 64 MiB) | Wt (F*D fp32, 128 MiB)
//   | cand (B*NC int) | vals (B*K) | idxs (B*K) | pre chunk (rpc * F fp32)
// ---------------------------------------------------------------------------
extern "C" void kernel_launch(void* const* d_in, const int* in_sizes, int n_in,
                              void* d_out, int out_size, void* d_ws, size_t ws_size,
                              hipStream_t stream) {
  (void)in_sizes; (void)n_in; (void)out_size;
  const float* x    = (const float*)d_in[0];
  const float* Wenc = (const float*)d_in[1];
  const float* benc = (const float*)d_in[2];
  const float* Wdec = (const float*)d_in[3];
  const float* bdec = (const float*)d_in[4];
  float* out = (float*)d_out;

  char* ws = (char*)d_ws;
  size_t off = 0;
  short* xb   = (short*)(ws + off); off += (size_t)Bn * Dd * 2;
  short* wb   = (short*)(ws + off); off += (size_t)Ff * Dd * 2;
  float* Wt   = (float*)(ws + off); off += (size_t)Ff * Dd * 4;
  int*   cand = (int*)(ws + off);   off += (size_t)Bn * NC * 4;
  float* vals = (float*)(ws + off); off += (size_t)Bn * Kk * 4;
  int*   idxs = (int*)(ws + off);   off += (size_t)Bn * Kk * 4;
  float* pre  = (float*)(ws + off);
  const size_t avail = ws_size > off ? ws_size - off : 0;
  int rpc = (int)(avail / ((size_t)Ff * 4));
  rpc = (rpc / 128) * 128;
  if (rpc < 128) rpc = 128;
  if (rpc > Bn) rpc = Bn;

  cvt_x_kernel<<<Bn * Dd / 1024, 256, 0, stream>>>(x, bdec, xb);
  cvt_w_kernel<<<Ff * Dd / 1024, 256, 0, stream>>>(Wenc, wb);
  transpose_kernel<<<dim3(Ff / 32, Dd / 32), dim3(32, 8), 0, stream>>>(Wdec, Wt);

  for (int r0 = 0; r0 < Bn; r0 += rpc) {
    const int rows = (Bn - r0 < rpc) ? (Bn - r0) : rpc;
    encode_mfma<<<dim3(Ff / 128, rows / 128), 256, 0, stream>>>(xb + (size_t)r0 * Dd, wb, benc, pre);
    screen_kernel<<<rows, 256, 0, stream>>>(pre, cand, r0);
  }

  rescore_np<<<Bn, 128, 0, stream>>>(x, Wenc, bdec, benc, cand, vals, idxs);
  decode_kernel<<<Bn, 256, 0, stream>>>(vals, idxs, Wt, bdec, out);
}